// Round 1
// baseline (331.743 us; speedup 1.0000x reference)
//
#include <hip/hip_runtime.h>
#include <hip/hip_bf16.h>

#define NN   100000
#define DD   128
#define ZZ   128
#define TT   1024
#define KK   256
#define HIDD 512
#define DIN  384

typedef __attribute__((ext_vector_type(8))) short  short8;   // 8 bf16 = 4 VGPRs (MFMA A/B frag)
typedef __attribute__((ext_vector_type(4))) float  f32x4;    // MFMA C/D frag
typedef __attribute__((ext_vector_type(4))) int    int4v;    // 16B copy

__device__ inline unsigned short f2bf(float f) {  // RTNE fp32 -> bf16
    union { float f; unsigned int u; } x; x.f = f;
    unsigned int r = x.u + 0x7fffu + ((x.u >> 16) & 1u);
    return (unsigned short)(r >> 16);
}

// ---------------- Kernel 1: zpe = z + pe@W_pe (bf16), ctx cast to bf16 ----------------
__global__ __launch_bounds__(256) void prep_tables(
    const float* __restrict__ pe, const float* __restrict__ ctx,
    const float* __restrict__ z, const float* __restrict__ wpe,
    unsigned short* __restrict__ ctx_bf, unsigned short* __restrict__ zpe_bf) {
    int g = blockIdx.x * 256 + threadIdx.x;
    if (g >= NN * DD) return;
    int n = g >> 7, j = g & 127;
    float acc = z[j];
    acc += pe[n * 4 + 0] * wpe[0 * ZZ + j];
    acc += pe[n * 4 + 1] * wpe[1 * ZZ + j];
    acc += pe[n * 4 + 2] * wpe[2 * ZZ + j];
    acc += pe[n * 4 + 3] * wpe[3 * ZZ + j];
    zpe_bf[g] = f2bf(acc);
    ctx_bf[g] = f2bf(ctx[g]);
}

// ---------------- Kernel 2: pack W1/W2 into bf16 MFMA B-fragment order ----------------
// B-frag tile (16 cols x 32 k): lane l elem e -> k_local = (l>>4)*8 + e, col = l&15.
// W1 tiles: tid1 = (hc*12 + kc)*8 + ntg   (hc:HID/128 chunk, kc:K/32, ntg:16-col tile)
// W2 tiles: tid2 = kcg*8 + ntg            (kcg:512/32, ntg: 128/16)
__global__ __launch_bounds__(256) void pack_w(
    const float* __restrict__ W1, const float* __restrict__ W2,
    unsigned short* __restrict__ w1p, unsigned short* __restrict__ w2p) {
    int g = blockIdx.x * 256 + threadIdx.x;
    if (g < DIN * HIDD) {
        int e = g & 7, l = (g >> 3) & 63, tile = g >> 9;
        int ntg = tile & 7, rem = tile >> 3;
        int kc = rem % 12, hc = rem / 12;
        int k = kc * 32 + (l >> 4) * 8 + e;
        int n = hc * 128 + ntg * 16 + (l & 15);
        w1p[g] = f2bf(W1[k * HIDD + n]);
    } else {
        int q = g - DIN * HIDD;
        if (q < HIDD * DD) {
            int e = q & 7, l = (q >> 3) & 63, tile = q >> 9;
            int ntg = tile & 7, kcg = tile >> 3;
            int k = kcg * 32 + (l >> 4) * 8 + e;
            int n = ntg * 16 + (l & 15);
            w2p[q] = f2bf(W2[k * DD + n]);
        }
    }
}

// ---------------- Kernel 3: fused gather + MLP + masked-MSE ----------------
// Block = (target t, 64-row K-tile). 4 waves. M=64. HID in 4 chunks of 128.
// LDS rows are 256B; XOR swizzle byte ^= (row&7)<<4 (G4: breaks 16-way ds_read_b128 conflict).
__global__ __launch_bounds__(256) void mp_jepa_main(
    const unsigned short* __restrict__ ctx_bf,
    const unsigned short* __restrict__ zpe_bf,
    const unsigned short* __restrict__ w1p,
    const unsigned short* __restrict__ w2p,
    const float* __restrict__ target_embedding,
    const int* __restrict__ sub_nodes,
    const int* __restrict__ sub_counts,
    const int* __restrict__ target_nodes,
    const float* __restrict__ b1,
    const float* __restrict__ b2,
    float* __restrict__ out) {
    const int bid = blockIdx.x;
    const int t = bid >> 2, kt = bid & 3;
    const int k0 = kt * 64;
    int cnt = sub_counts[t]; if (cnt < 1) cnt = 1;
    if (k0 >= cnt) return;           // uniform early-exit before any barrier
    const int tgt = target_nodes[t];

    __shared__ __align__(16) unsigned short ctxT[64 * 128];  // 16 KB, swizzled
    __shared__ __align__(16) unsigned short zpeT[64 * 128];  // 16 KB, swizzled
    __shared__ __align__(16) unsigned short hT[64 * 128];    // 16 KB, swizzled
    __shared__ __align__(16) unsigned short ztg[128];        // z+pe of target (broadcast row)
    __shared__ float tgte[128];
    __shared__ float b1s[HIDD];
    __shared__ float b2s[128];
    __shared__ int   idxs[64];
    __shared__ float red[4];

    const int tid = threadIdx.x;
    const int w = tid >> 6, l = tid & 63;
    const int lo = l & 15, hi = l >> 4;

    if (tid < 64) idxs[tid] = sub_nodes[t * KK + k0 + tid];
    if (tid < 128) {
        ztg[tid]  = zpe_bf[(size_t)tgt * 128 + tid];
        tgte[tid] = target_embedding[(size_t)tgt * 128 + tid];
        b2s[tid]  = b2[tid];
    }
    b1s[tid]       = b1[tid];
    b1s[tid + 256] = b1[tid + 256];
    __syncthreads();

    // Stage gathered ctx/zpe rows (bf16) into swizzled LDS: 64 rows x 256B each.
#pragma unroll
    for (int it = 0; it < 4; ++it) {
        int u = it * 256 + tid;               // 0..1023: (row, 16B-chunk)
        int row = u >> 4, cc = u & 15;
        size_t node = (size_t)idxs[row];
        int cb = cc * 16;
        int dst = (row * 256 + (cb ^ ((row & 7) << 4))) >> 1;   // ushort index
        int4v vc = *((const int4v*)(ctx_bf + node * 128) + cc);
        int4v vz = *((const int4v*)(zpe_bf + node * 128) + cc);
        *(int4v*)(ctxT + dst) = vc;
        *(int4v*)(zpeT + dst) = vz;
    }
    __syncthreads();

    const short8* w1v = (const short8*)w1p;
    const short8* w2v = (const short8*)w2p;

    f32x4 accP[4][2];
#pragma unroll
    for (int rg = 0; rg < 4; ++rg)
#pragma unroll
        for (int nt = 0; nt < 2; ++nt) accP[rg][nt] = (f32x4){0.f, 0.f, 0.f, 0.f};

    for (int hc = 0; hc < 4; ++hc) {
        // ---- GEMM1 chunk: h[64, 128cols@hc] = agg[64,384] @ W1[:, hc*128..]
        f32x4 acc1[4][2];
#pragma unroll
        for (int rg = 0; rg < 4; ++rg)
#pragma unroll
            for (int nt = 0; nt < 2; ++nt) acc1[rg][nt] = (f32x4){0.f, 0.f, 0.f, 0.f};

#pragma unroll
        for (int kc = 0; kc < 12; ++kc) {
            short8 bf0 = w1v[((((hc * 12 + kc) << 3) + (w << 1) + 0)) * 64 + l];
            short8 bf1 = w1v[((((hc * 12 + kc) << 3) + (w << 1) + 1)) * 64 + l];
            short8 a[4];
            if (kc < 8) {
                const unsigned short* src = (kc < 4) ? ctxT : zpeT;
                int cb = ((kc & 3) << 6) + (hi << 4);
#pragma unroll
                for (int rg = 0; rg < 4; ++rg) {
                    int row = (rg << 4) + lo;
                    a[rg] = *(const short8*)(src + ((row * 256 + (cb ^ ((row & 7) << 4))) >> 1));
                }
            } else {  // z_tgt part: identical for every row -> broadcast read
                int cb = ((kc - 8) << 6) + (hi << 4);
                short8 az = *(const short8*)(ztg + (cb >> 1));
                a[0] = az; a[1] = az; a[2] = az; a[3] = az;
            }
#pragma unroll
            for (int rg = 0; rg < 4; ++rg) {
                acc1[rg][0] = __builtin_amdgcn_mfma_f32_16x16x32_bf16(a[rg], bf0, acc1[rg][0], 0, 0, 0);
                acc1[rg][1] = __builtin_amdgcn_mfma_f32_16x16x32_bf16(a[rg], bf1, acc1[rg][1], 0, 0, 0);
            }
        }

        __syncthreads();  // prior GEMM2 finished reading hT
        // relu(acc1 + b1) -> bf16 -> swizzled hT
#pragma unroll
        for (int nt = 0; nt < 2; ++nt) {
            int col = (w << 5) + (nt << 4) + lo;
            float bb = b1s[(hc << 7) + col];
#pragma unroll
            for (int rg = 0; rg < 4; ++rg) {
#pragma unroll
                for (int r = 0; r < 4; ++r) {
                    int row = (rg << 4) + (hi << 2) + r;
                    float v = acc1[rg][nt][r] + bb;
                    v = v > 0.f ? v : 0.f;
                    hT[(row * 256 + ((col * 2) ^ ((row & 7) << 4))) >> 1] = f2bf(v);
                }
            }
        }
        __syncthreads();

        // ---- GEMM2 partial: pred += relu_h[64,128] @ W2[hc*128.., 128]
#pragma unroll
        for (int kc2 = 0; kc2 < 4; ++kc2) {
            int kcg = (hc << 2) + kc2;
            short8 bg0 = w2v[(((kcg << 3) + (w << 1) + 0)) * 64 + l];
            short8 bg1 = w2v[(((kcg << 3) + (w << 1) + 1)) * 64 + l];
            int cb = (kc2 << 6) + (hi << 4);
#pragma unroll
            for (int rg = 0; rg < 4; ++rg) {
                int row = (rg << 4) + lo;
                short8 a = *(const short8*)(hT + ((row * 256 + (cb ^ ((row & 7) << 4))) >> 1));
                accP[rg][0] = __builtin_amdgcn_mfma_f32_16x16x32_bf16(a, bg0, accP[rg][0], 0, 0, 0);
                accP[rg][1] = __builtin_amdgcn_mfma_f32_16x16x32_bf16(a, bg1, accP[rg][1], 0, 0, 0);
            }
        }
    }

    // ---- masked squared error + reduction
    float s = 0.f;
#pragma unroll
    for (int nt = 0; nt < 2; ++nt) {
        int col = (w << 5) + (nt << 4) + lo;
        float bb = b2s[col] - tgte[col];
#pragma unroll
        for (int rg = 0; rg < 4; ++rg) {
#pragma unroll
            for (int r = 0; r < 4; ++r) {
                int row = (rg << 4) + (hi << 2) + r;   // C/D: col=lane&15, row=(lane>>4)*4+r
                float d = accP[rg][nt][r] + bb;
                if (k0 + row < cnt) s += d * d;
            }
        }
    }
#pragma unroll
    for (int off = 32; off > 0; off >>= 1) s += __shfl_xor(s, off, 64);
    if (l == 0) red[w] = s;
    __syncthreads();
    if (tid == 0) {
        float tot = (red[0] + red[1] + red[2] + red[3]) / ((float)cnt * 128.0f);
        atomicAdd(out, tot);
    }
}

extern "C" void kernel_launch(void* const* d_in, const int* in_sizes, int n_in,
                              void* d_out, int out_size, void* d_ws, size_t ws_size,
                              hipStream_t stream) {
    const float* pe           = (const float*)d_in[0];
    const float* ctx          = (const float*)d_in[1];
    const float* tgt_emb      = (const float*)d_in[2];
    const int*   sub_nodes    = (const int*)d_in[3];
    const int*   sub_counts   = (const int*)d_in[4];
    const int*   target_nodes = (const int*)d_in[5];
    const float* z            = (const float*)d_in[6];
    const float* wpe          = (const float*)d_in[7];
    const float* W1           = (const float*)d_in[8];
    const float* b1           = (const float*)d_in[9];
    const float* W2           = (const float*)d_in[10];
    const float* b2           = (const float*)d_in[11];
    float* out = (float*)d_out;

    char* ws = (char*)d_ws;
    unsigned short* ctx_bf = (unsigned short*)ws;                          // 25.6 MB
    unsigned short* zpe_bf = (unsigned short*)(ws + 25600000);             // 25.6 MB
    unsigned short* w1p    = (unsigned short*)(ws + 51200000);             // 384 KB
    unsigned short* w2p    = (unsigned short*)(ws + 51200000 + 393216);    // 128 KB

    hipMemsetAsync(d_out, 0, sizeof(float), stream);  // d_out is re-poisoned each call
    prep_tables<<<(NN * DD + 255) / 256, 256, 0, stream>>>(pe, ctx, z, wpe, ctx_bf, zpe_bf);
    pack_w<<<(DIN * HIDD + HIDD * DD + 255) / 256, 256, 0, stream>>>(W1, W2, w1p, w2p);
    mp_jepa_main<<<TT * 4, 256, 0, stream>>>(ctx_bf, zpe_bf, w1p, w2p, tgt_emb,
                                             sub_nodes, sub_counts, target_nodes, b1, b2, out);
}

// Round 2
// 270.830 us; speedup vs baseline: 1.2249x; 1.2249x over previous
//
#include <hip/hip_runtime.h>
#include <hip/hip_bf16.h>

#define NN   100000
#define DD   128
#define ZZ   128
#define TT   1024
#define KK   256
#define HIDD 512

typedef __attribute__((ext_vector_type(8))) short  short8;   // 8 bf16 (MFMA A/B frag)
typedef __attribute__((ext_vector_type(4))) float  f32x4;    // MFMA C/D frag

__device__ inline unsigned short f2bf(float f) {  // RTNE fp32 -> bf16
    union { float f; unsigned int u; } x; x.f = f;
    unsigned int r = x.u + 0x7fffu + ((x.u >> 16) & 1u);
    return (unsigned short)(r >> 16);
}
__device__ inline float bf2f(unsigned short u) {
    union { unsigned int u; float f; } x; x.u = ((unsigned int)u) << 16;
    return x.f;
}
__device__ inline void load_lds16(const void* g, void* l) {
    __builtin_amdgcn_global_load_lds((const __attribute__((address_space(1))) unsigned int*)g,
                                     (__attribute__((address_space(3))) unsigned int*)l, 16, 0, 0);
}

// ---------------- Kernel 1: zpe = z + pe@W_pe (bf16), ctx cast to bf16 — 8 elems/thread ----------------
__global__ __launch_bounds__(256) void prep_tables(
    const float* __restrict__ pe, const float* __restrict__ ctx,
    const float* __restrict__ z, const float* __restrict__ wpe,
    unsigned short* __restrict__ ctx_bf, unsigned short* __restrict__ zpe_bf) {
    int g = blockIdx.x * 256 + threadIdx.x;      // one thread per 8 elements
    if (g >= NN * 16) return;
    int n = g >> 4, j8 = (g & 15) << 3;
    float p0 = pe[n * 4 + 0], p1 = pe[n * 4 + 1], p2 = pe[n * 4 + 2], p3 = pe[n * 4 + 3];
    float4 c0 = *(const float4*)(ctx + (size_t)n * 128 + j8);
    float4 c1 = *(const float4*)(ctx + (size_t)n * 128 + j8 + 4);
    float4 z0 = *(const float4*)(z + j8);
    float4 z1 = *(const float4*)(z + j8 + 4);
    float4 wa0 = *(const float4*)(wpe + 0 * ZZ + j8), wa1 = *(const float4*)(wpe + 0 * ZZ + j8 + 4);
    float4 wb0 = *(const float4*)(wpe + 1 * ZZ + j8), wb1 = *(const float4*)(wpe + 1 * ZZ + j8 + 4);
    float4 wc0 = *(const float4*)(wpe + 2 * ZZ + j8), wc1 = *(const float4*)(wpe + 2 * ZZ + j8 + 4);
    float4 wd0 = *(const float4*)(wpe + 3 * ZZ + j8), wd1 = *(const float4*)(wpe + 3 * ZZ + j8 + 4);
    float zp[8], cv[8];
    zp[0] = z0.x + p0 * wa0.x + p1 * wb0.x + p2 * wc0.x + p3 * wd0.x;
    zp[1] = z0.y + p0 * wa0.y + p1 * wb0.y + p2 * wc0.y + p3 * wd0.y;
    zp[2] = z0.z + p0 * wa0.z + p1 * wb0.z + p2 * wc0.z + p3 * wd0.z;
    zp[3] = z0.w + p0 * wa0.w + p1 * wb0.w + p2 * wc0.w + p3 * wd0.w;
    zp[4] = z1.x + p0 * wa1.x + p1 * wb1.x + p2 * wc1.x + p3 * wd1.x;
    zp[5] = z1.y + p0 * wa1.y + p1 * wb1.y + p2 * wc1.y + p3 * wd1.y;
    zp[6] = z1.z + p0 * wa1.z + p1 * wb1.z + p2 * wc1.z + p3 * wd1.z;
    zp[7] = z1.w + p0 * wa1.w + p1 * wb1.w + p2 * wc1.w + p3 * wd1.w;
    cv[0] = c0.x; cv[1] = c0.y; cv[2] = c0.z; cv[3] = c0.w;
    cv[4] = c1.x; cv[5] = c1.y; cv[6] = c1.z; cv[7] = c1.w;
    short8 sz, sc;
#pragma unroll
    for (int i = 0; i < 8; ++i) { sz[i] = (short)f2bf(zp[i]); sc[i] = (short)f2bf(cv[i]); }
    *(short8*)(zpe_bf + (size_t)g * 8) = sz;
    *(short8*)(ctx_bf + (size_t)g * 8) = sc;
}

// ---------------- Kernel 2: pack W1(k<256)/W2 into bf16 MFMA B-fragment order ----------------
// B-frag tile (16 cols x 32 k): lane l elem e -> k_local = (l>>4)*8 + e, col = l&15.
__global__ __launch_bounds__(256) void pack_w(
    const float* __restrict__ W1, const float* __restrict__ W2,
    unsigned short* __restrict__ w1p, unsigned short* __restrict__ w2p) {
    int g = blockIdx.x * 256 + threadIdx.x;
    if (g < 256 * HIDD) {                         // W1 rows 0..255 (ctx|zpe parts)
        int e = g & 7, l = (g >> 3) & 63, tile = g >> 9;
        int ntg = tile & 7, rem = tile >> 3;      // rem = hc*8 + kc
        int kc = rem & 7, hc = rem >> 3;
        int k = kc * 32 + (l >> 4) * 8 + e;
        int n = hc * 128 + ntg * 16 + (l & 15);
        w1p[g] = f2bf(W1[(size_t)k * HIDD + n]);
    } else {
        int q = g - 256 * HIDD;
        if (q < HIDD * DD) {
            int e = q & 7, l = (q >> 3) & 63, tile = q >> 9;
            int ntg = tile & 7, kcg = tile >> 3;
            int k = kcg * 32 + (l >> 4) * 8 + e;
            int n = ntg * 16 + (l & 15);
            w2p[q] = f2bf(W2[(size_t)k * DD + n]);
        }
    }
}

// ---------------- Kernel 2b: ct[t][512] = b1 + (z+pe_tgt) @ W1c  (8 targets/block) ----------------
__global__ __launch_bounds__(256) void ct_kernel(
    const unsigned short* __restrict__ zpe_bf, const int* __restrict__ target_nodes,
    const float* __restrict__ W1, const float* __restrict__ b1, float* __restrict__ ct_g) {
    __shared__ float zp[8][128];
    int b = blockIdx.x, tid = threadIdx.x;
#pragma unroll
    for (int q = 0; q < 4; ++q) {
        int idx = q * 256 + tid;                  // 0..1023
        int t8 = idx >> 7, zz = idx & 127;
        int tgt = target_nodes[b * 8 + t8];
        zp[t8][zz] = bf2f(zpe_bf[(size_t)tgt * 128 + zz]);
    }
    __syncthreads();
    int j0 = tid, j1 = tid + 256;
    float a0[8], a1[8];
    float bb0 = b1[j0], bb1 = b1[j1];
#pragma unroll
    for (int t8 = 0; t8 < 8; ++t8) { a0[t8] = bb0; a1[t8] = bb1; }
#pragma unroll 8
    for (int zz = 0; zz < 128; ++zz) {
        float w0 = W1[(size_t)(256 + zz) * HIDD + j0];
        float w1 = W1[(size_t)(256 + zz) * HIDD + j1];
#pragma unroll
        for (int t8 = 0; t8 < 8; ++t8) { a0[t8] += zp[t8][zz] * w0; a1[t8] += zp[t8][zz] * w1; }
    }
#pragma unroll
    for (int t8 = 0; t8 < 8; ++t8) {
        ct_g[(size_t)(b * 8 + t8) * HIDD + j0] = a0[t8];
        ct_g[(size_t)(b * 8 + t8) * HIDD + j1] = a1[t8];
    }
}

// ---------------- Kernel 3: fused gather + MLP + masked-MSE ----------------
// Block = (target t, 64-row K-tile). 4 waves. HID in 4 chunks of 128.
// ctx/zpe LDS: rows 256B, swizzle byte ^= ((row&7)<<4) (b128 reads at balanced 8-clk floor).
// hT LDS: swizzle byte ^= ((row>>2)&3)<<5  -> b16 writes spread over all 32 banks (~free),
//         b128 reads still balanced floor.
__global__ __launch_bounds__(256, 3) void mp_jepa_main(
    const unsigned short* __restrict__ ctx_bf,
    const unsigned short* __restrict__ zpe_bf,
    const unsigned short* __restrict__ w1p,
    const unsigned short* __restrict__ w2p,
    const float* __restrict__ ct_g,
    const float* __restrict__ target_embedding,
    const int* __restrict__ sub_nodes,
    const int* __restrict__ sub_counts,
    const int* __restrict__ target_nodes,
    const float* __restrict__ b2,
    float* __restrict__ out) {
    const int bid = blockIdx.x;
    const int t = bid >> 2, kt = bid & 3;
    const int k0 = kt * 64;
    int cnt = sub_counts[t]; if (cnt < 1) cnt = 1;
    if (k0 >= cnt) return;           // uniform early-exit before any barrier
    const int tgt = target_nodes[t];

    __shared__ __align__(16) unsigned short ctxT[64 * 128];  // 16 KB
    __shared__ __align__(16) unsigned short zpeT[64 * 128];  // 16 KB
    __shared__ __align__(16) unsigned short hT[64 * 128];    // 16 KB
    __shared__ float cts[HIDD];
    __shared__ float tgte[DD];
    __shared__ float b2s[DD];
    __shared__ float red[4];

    const int tid = threadIdx.x;
    const int w = tid >> 6, l = tid & 63;
    const int lo = l & 15, hi = l >> 4;

    // Async gather: linear LDS dest (base + lane*16), inverse-swizzled global source.
    {
        const char* cc = (const char*)ctx_bf;
        const char* zc = (const char*)zpe_bf;
        const int base = t * KK + k0;
#pragma unroll
        for (int it = 0; it < 4; ++it) {
            int rgrp = it * 16 + (w << 2);        // wave-uniform row-group base (4 rows)
            int row  = rgrp + hi;
            int node = sub_nodes[base + row];
            int soff = (lo << 4) ^ ((row & 7) << 4);
            load_lds16(cc + (size_t)node * 256 + soff, (char*)ctxT + rgrp * 256);
            load_lds16(zc + (size_t)node * 256 + soff, (char*)zpeT + rgrp * 256);
        }
    }
    // params load overlaps the in-flight gather
    if (tid < 128) {
        tgte[tid] = target_embedding[(size_t)tgt * 128 + tid];
        b2s[tid]  = b2[tid];
    }
    cts[tid]       = ct_g[(size_t)t * HIDD + tid];
    cts[tid + 256] = ct_g[(size_t)t * HIDD + tid + 256];
    __syncthreads();

    const short8* w1v = (const short8*)w1p;
    const short8* w2v = (const short8*)w2p;

    f32x4 accP[4][2];
#pragma unroll
    for (int rg = 0; rg < 4; ++rg)
#pragma unroll
        for (int nt = 0; nt < 2; ++nt) accP[rg][nt] = (f32x4){0.f, 0.f, 0.f, 0.f};

    for (int hc = 0; hc < 4; ++hc) {
        // ---- GEMM1 chunk: h[64,128@hc] = [ctx|zpe][64,256] @ W1ab[:,hc] + ct (C-init)
        f32x4 acc1[4][2];
#pragma unroll
        for (int nt = 0; nt < 2; ++nt) {
            float c = cts[(hc << 7) + (w << 5) + (nt << 4) + lo];
#pragma unroll
            for (int rg = 0; rg < 4; ++rg) acc1[rg][nt] = (f32x4){c, c, c, c};
        }
#pragma unroll
        for (int kc = 0; kc < 8; ++kc) {
            int fb = ((hc << 3) + kc) << 3;
            short8 bf0 = w1v[(fb + (w << 1) + 0) * 64 + l];
            short8 bf1 = w1v[(fb + (w << 1) + 1) * 64 + l];
            const unsigned short* src = (kc < 4) ? ctxT : zpeT;
            int cb = ((kc & 3) << 6) + (hi << 4);
            short8 a[4];
#pragma unroll
            for (int rg = 0; rg < 4; ++rg) {
                int row = (rg << 4) + lo;
                a[rg] = *(const short8*)(src + ((row * 256 + (cb ^ ((row & 7) << 4))) >> 1));
            }
#pragma unroll
            for (int rg = 0; rg < 4; ++rg) {
                acc1[rg][0] = __builtin_amdgcn_mfma_f32_16x16x32_bf16(a[rg], bf0, acc1[rg][0], 0, 0, 0);
                acc1[rg][1] = __builtin_amdgcn_mfma_f32_16x16x32_bf16(a[rg], bf1, acc1[rg][1], 0, 0, 0);
            }
        }

        __syncthreads();  // prior GEMM2 finished reading hT
        // relu -> bf16 -> swizzled hT (no bias add: folded into ct C-init)
#pragma unroll
        for (int nt = 0; nt < 2; ++nt) {
            int col2 = ((w << 5) + (nt << 4) + lo) << 1;
#pragma unroll
            for (int rg = 0; rg < 4; ++rg) {
#pragma unroll
                for (int r = 0; r < 4; ++r) {
                    int row = (rg << 4) + (hi << 2) + r;
                    float v = acc1[rg][nt][r];
                    v = v > 0.f ? v : 0.f;
                    hT[(row * 256 + (col2 ^ ((row & 0xC) << 3))) >> 1] = f2bf(v);
                }
            }
        }
        __syncthreads();

        // ---- GEMM2 partial: pred += relu_h[64,128] @ W2[hc*128.., 128]
#pragma unroll
        for (int kc2 = 0; kc2 < 4; ++kc2) {
            int kcg = (hc << 2) + kc2;
            short8 bg0 = w2v[(((kcg << 3) + (w << 1) + 0)) * 64 + l];
            short8 bg1 = w2v[(((kcg << 3) + (w << 1) + 1)) * 64 + l];
            int cb = (kc2 << 6) + (hi << 4);
#pragma unroll
            for (int rg = 0; rg < 4; ++rg) {
                int row = (rg << 4) + lo;
                short8 a = *(const short8*)(hT + ((row * 256 + (cb ^ ((row & 0xC) << 3))) >> 1));
                accP[rg][0] = __builtin_amdgcn_mfma_f32_16x16x32_bf16(a, bg0, accP[rg][0], 0, 0, 0);
                accP[rg][1] = __builtin_amdgcn_mfma_f32_16x16x32_bf16(a, bg1, accP[rg][1], 0, 0, 0);
            }
        }
    }

    // ---- masked squared error + reduction
    float s = 0.f;
#pragma unroll
    for (int nt = 0; nt < 2; ++nt) {
        int col = (w << 5) + (nt << 4) + lo;
        float bb = b2s[col] - tgte[col];
#pragma unroll
        for (int rg = 0; rg < 4; ++rg) {
#pragma unroll
            for (int r = 0; r < 4; ++r) {
                int row = (rg << 4) + (hi << 2) + r;   // C/D: col=lane&15, row=(lane>>4)*4+r
                float d = accP[rg][nt][r] + bb;
                if (k0 + row < cnt) s += d * d;
            }
        }
    }
#pragma unroll
    for (int off = 32; off > 0; off >>= 1) s += __shfl_xor(s, off, 64);
    if (l == 0) red[w] = s;
    __syncthreads();
    if (tid == 0) {
        float tot = (red[0] + red[1] + red[2] + red[3]) / ((float)cnt * 128.0f);
        atomicAdd(out, tot);
    }
}

extern "C" void kernel_launch(void* const* d_in, const int* in_sizes, int n_in,
                              void* d_out, int out_size, void* d_ws, size_t ws_size,
                              hipStream_t stream) {
    const float* pe           = (const float*)d_in[0];
    const float* ctx          = (const float*)d_in[1];
    const float* tgt_emb      = (const float*)d_in[2];
    const int*   sub_nodes    = (const int*)d_in[3];
    const int*   sub_counts   = (const int*)d_in[4];
    const int*   target_nodes = (const int*)d_in[5];
    const float* z            = (const float*)d_in[6];
    const float* wpe          = (const float*)d_in[7];
    const float* W1           = (const float*)d_in[8];
    const float* b1           = (const float*)d_in[9];
    const float* W2           = (const float*)d_in[10];
    const float* b2           = (const float*)d_in[11];
    float* out = (float*)d_out;

    char* ws = (char*)d_ws;
    unsigned short* ctx_bf = (unsigned short*)ws;                              // 25.6 MB
    unsigned short* zpe_bf = (unsigned short*)(ws + 25600000);                 // 25.6 MB
    unsigned short* w1p    = (unsigned short*)(ws + 51200000);                 // 256 KB
    unsigned short* w2p    = (unsigned short*)(ws + 51200000 + 262144);        // 128 KB
    float*          ct_g   = (float*)(ws + 51200000 + 262144 + 131072);        // 2 MB

    hipMemsetAsync(d_out, 0, sizeof(float), stream);
    prep_tables<<<(NN * 16 + 255) / 256, 256, 0, stream>>>(pe, ctx, z, wpe, ctx_bf, zpe_bf);
    pack_w<<<(256 * HIDD + HIDD * DD + 255) / 256, 256, 0, stream>>>(W1, W2, w1p, w2p);
    ct_kernel<<<TT / 8, 256, 0, stream>>>(zpe_bf, target_nodes, W1, b1, ct_g);
    mp_jepa_main<<<TT * 4, 256, 0, stream>>>(ctx_bf, zpe_bf, w1p, w2p, ct_g, tgt_emb,
                                             sub_nodes, sub_counts, target_nodes, b2, out);
}